// Round 3
// baseline (37.995 us; speedup 1.0000x reference)
//
#include <hip/hip_runtime.h>
#include <math.h>

#define B 8
#define N 2048
#define D 3072
#define K1_BLOCKS 512
#define NPB (N / K1_BLOCKS)      // 4 training rows per K1 block
#define NCHUNK 128
#define CHUNK (N / NCHUNK)       // 16

// ---- device helpers ----------------------------------------------------

struct Scalars {
    float state_scale;  // sqrt(1 + var_tilde)
    float inv_2vt;      // 1 / (2 * var_tilde)
    float alpha;
    float inv_sigma;
};

__device__ inline Scalars compute_scalars(const float* __restrict__ ng) {
    float gamma = ng[0] * 25.0f - 15.0f;            // *(GAMMA_MAX-GAMMA_MIN)+GAMMA_MIN
    float var_tilde = expf(-gamma);
    float variance = 1.0f / (1.0f + expf(gamma));   // sigmoid(-gamma)
    Scalars s;
    s.state_scale = sqrtf(1.0f + var_tilde);
    s.inv_2vt     = 0.5f / var_tilde;
    s.alpha       = sqrtf(1.0f - variance);
    s.inv_sigma   = 1.0f / sqrtf(variance);
    return s;
}

// ---- K1: sse[b][n] = sum_d ((in[b,d]*ss - train[n,d]) * mask[d])^2 -----
// 512 blocks x 256 threads; each block owns NPB=4 training rows.
// Pre-scaled masked input slice lives in registers (compile-time indexed),
// reused across the block's rows. f64 accumulation for argmax robustness.

__global__ __launch_bounds__(256, 2) void k_sse(
        const float* __restrict__ in, const float* __restrict__ ng,
        const float* __restrict__ mask, const float* __restrict__ train,
        float* __restrict__ sse_out) {
    const int tid = threadIdx.x;
    const int n0  = blockIdx.x * NPB;
    const Scalars sc = compute_scalars(ng);

    // register-resident slice: sm[k][b] = in[b,d]*ss*m[d], m4[k] = mask
    float4 sm[3][B];
    float4 m4[3];
#pragma unroll
    for (int k = 0; k < 3; ++k) {
        const int d = (tid + k * 256) * 4;
        m4[k] = *(const float4*)(mask + d);
#pragma unroll
        for (int b = 0; b < B; ++b) {
            const float4 s = *(const float4*)(in + b * D + d);
            sm[k][b].x = s.x * sc.state_scale * m4[k].x;
            sm[k][b].y = s.y * sc.state_scale * m4[k].y;
            sm[k][b].z = s.z * sc.state_scale * m4[k].z;
            sm[k][b].w = s.w * sc.state_scale * m4[k].w;
        }
    }

    __shared__ double red[NPB][4][B];
    const int wave = tid >> 6, lane = tid & 63;

#pragma unroll
    for (int j = 0; j < NPB; ++j) {
        const float* trow = train + (size_t)(n0 + j) * D;
        double acc[B];
#pragma unroll
        for (int b = 0; b < B; ++b) acc[b] = 0.0;

#pragma unroll
        for (int k = 0; k < 3; ++k) {
            const int d = (tid + k * 256) * 4;
            const float4 t = *(const float4*)(trow + d);
            float4 tm;
            tm.x = t.x * m4[k].x;
            tm.y = t.y * m4[k].y;
            tm.z = t.z * m4[k].z;
            tm.w = t.w * m4[k].w;
#pragma unroll
            for (int b = 0; b < B; ++b) {
                float dx = sm[k][b].x - tm.x;
                float dy = sm[k][b].y - tm.y;
                float dz = sm[k][b].z - tm.z;
                float dw = sm[k][b].w - tm.w;
                acc[b] += (double)dx * dx + (double)dy * dy
                        + (double)dz * dz + (double)dw * dw;
            }
        }

#pragma unroll
        for (int b = 0; b < B; ++b)
            for (int off = 32; off; off >>= 1)
                acc[b] += __shfl_down(acc[b], off);
        if (lane == 0) {
#pragma unroll
            for (int b = 0; b < B; ++b) red[j][wave][b] = acc[b];
        }
    }
    __syncthreads();
    if (tid < NPB * B) {
        const int j = tid >> 3, b = tid & 7;
        double s = red[j][0][b] + red[j][1][b] + red[j][2][b] + red[j][3][b];
        sse_out[b * N + (n0 + j)] = (float)s;
    }
}

// ---- K2: softmax over n per b; single pass, values in registers ---------
// writes probT[n*8 + b]

__global__ __launch_bounds__(256) void k_softmax(
        const float* __restrict__ sse, const float* __restrict__ ng,
        float* __restrict__ probT) {
    const int b   = blockIdx.x;
    const int tid = threadIdx.x;
    const Scalars sc = compute_scalars(ng);
    const float* row = sse + b * N;

    float v[N / 256];                                // 8 values per thread
#pragma unroll
    for (int k = 0; k < N / 256; ++k)
        v[k] = -row[tid + k * 256] * sc.inv_2vt;

    float mx = v[0];
#pragma unroll
    for (int k = 1; k < N / 256; ++k) mx = fmaxf(mx, v[k]);
    for (int off = 32; off; off >>= 1)
        mx = fmaxf(mx, __shfl_xor(mx, off));
    __shared__ float smx[4];
    if ((tid & 63) == 0) smx[tid >> 6] = mx;
    __syncthreads();
    mx = fmaxf(fmaxf(smx[0], smx[1]), fmaxf(smx[2], smx[3]));

    float e[N / 256];
    float sum = 0.0f;
#pragma unroll
    for (int k = 0; k < N / 256; ++k) {
        e[k] = expf(v[k] - mx);
        sum += e[k];
    }
    for (int off = 32; off; off >>= 1)
        sum += __shfl_xor(sum, off);
    __shared__ float ssum[4];
    if ((tid & 63) == 0) ssum[tid >> 6] = sum;
    __syncthreads();
    const float inv = 1.0f / (ssum[0] + ssum[1] + ssum[2] + ssum[3]);

#pragma unroll
    for (int k = 0; k < N / 256; ++k)
        probT[(tid + k * 256) * B + b] = e[k] * inv;
}

// ---- K3: partial denoised sums over n-chunks ----------------------------
// grid (12, NCHUNK=128) x 64 threads = 1536 blocks (6 waves/CU).
// CHUNK=16 fully unrolled -> 16-deep load pipeline.
// partials[(c*B + b)*D + d] = sum_{n in chunk c} probT[n][b] * train[n][d]

__device__ inline void fma4(float4& a, float p, const float4& t) {
    a.x = fmaf(p, t.x, a.x);
    a.y = fmaf(p, t.y, a.y);
    a.z = fmaf(p, t.z, a.z);
    a.w = fmaf(p, t.w, a.w);
}

__global__ __launch_bounds__(64) void k_denoise_partial(
        const float* __restrict__ train, const float* __restrict__ probT,
        float* __restrict__ partials) {
    const int d = (blockIdx.x * 64 + threadIdx.x) * 4;
    const int c = blockIdx.y;

    float4 acc[B];
#pragma unroll
    for (int b = 0; b < B; ++b) acc[b] = make_float4(0.f, 0.f, 0.f, 0.f);

    const int n0 = c * CHUNK;
#pragma unroll
    for (int i = 0; i < CHUNK; ++i) {
        const int n = n0 + i;
        const float4 t  = *(const float4*)(train + (size_t)n * D + d);
        const float4 p0 = *(const float4*)(probT + n * B);
        const float4 p1 = *(const float4*)(probT + n * B + 4);
        fma4(acc[0], p0.x, t); fma4(acc[1], p0.y, t);
        fma4(acc[2], p0.z, t); fma4(acc[3], p0.w, t);
        fma4(acc[4], p1.x, t); fma4(acc[5], p1.y, t);
        fma4(acc[6], p1.z, t); fma4(acc[7], p1.w, t);
    }
#pragma unroll
    for (int b = 0; b < B; ++b)
        *(float4*)(partials + ((size_t)(c * B + b)) * D + d) = acc[b];
}

// ---- K4: reduce partials + epilogue -------------------------------------
// 384 blocks x 64 threads; thread = one output element, 128 chunk partials
// with unroll-16 MLP.

__global__ __launch_bounds__(64) void k_eps(
        const float* __restrict__ in, const float* __restrict__ ng,
        const float* __restrict__ mask, const float* __restrict__ partials,
        float* __restrict__ out) {
    const int i = blockIdx.x * 64 + threadIdx.x;     // < B*D
    const int b = i / D;
    const int d = i - b * D;
    const Scalars sc = compute_scalars(ng);

    float s = 0.0f;
#pragma unroll 16
    for (int c = 0; c < NCHUNK; ++c)
        s += partials[((size_t)(c * B + b)) * D + d];

    out[i] = (in[i] - sc.alpha * s) * sc.inv_sigma * mask[d];
}

// ---- launch --------------------------------------------------------------

extern "C" void kernel_launch(void* const* d_in, const int* in_sizes, int n_in,
                              void* d_out, int out_size, void* d_ws, size_t ws_size,
                              hipStream_t stream) {
    const float* in    = (const float*)d_in[0];   // [8,3,32,32]
    const float* ng    = (const float*)d_in[1];   // [1]
    const float* mask  = (const float*)d_in[2];   // [3,32,32]
    const float* train = (const float*)d_in[3];   // [2048,3,32,32]
    float* out = (float*)d_out;

    float* ws       = (float*)d_ws;
    float* sse      = ws;                  // B*N   = 16384 floats
    float* probT    = ws + B * N;          // N*B   = 16384 floats
    float* partials = ws + 2 * B * N;      // NCHUNK*B*D = 3.1M floats (12.6 MB)

    k_sse<<<K1_BLOCKS, 256, 0, stream>>>(in, ng, mask, train, sse);
    k_softmax<<<B, 256, 0, stream>>>(sse, ng, probT);
    k_denoise_partial<<<dim3(D / 4 / 64, NCHUNK), 64, 0, stream>>>(train, probT, partials);
    k_eps<<<(B * D) / 64, 64, 0, stream>>>(in, ng, mask, partials, out);
}